// Round 5
// baseline (17664.545 us; speedup 1.0000x reference)
//
#include <hip/hip_runtime.h>
#include <cstdint>
#include <cstddef>

static constexpr int BS  = 128;
static constexpr int RAL = 1024;
static constexpr int LAL = 256;
static constexpr int CS  = 256;
static constexpr int VOC = 34;
static constexpr int HFS = 512;
static constexpr int EMB = 256;

static constexpr int NSPLIT = 2;
static constexpr int RSPL   = RAL / NSPLIT;   // 512 max rows per split block
static constexpr int NBLK   = 256;            // proven co-resident

typedef float  f32x4  __attribute__((ext_vector_type(4)));
typedef short  bf16x8 __attribute__((ext_vector_type(8)));

#define SC_AGENT __HIP_MEMORY_SCOPE_AGENT

static __device__ __forceinline__ float bflo(unsigned int u) {
    return __builtin_bit_cast(float, u << 16);
}
static __device__ __forceinline__ float bfhi(unsigned int u) {
    return __builtin_bit_cast(float, u & 0xffff0000u);
}
static __device__ __forceinline__ unsigned short f2bf(float f) {
    unsigned int x = __builtin_bit_cast(unsigned int, f);
    x = (x + 0x7fffu + ((x >> 16) & 1u)) >> 16;   // RNE
    return (unsigned short)x;
}
static __device__ __forceinline__ float bcf(unsigned u) { return __builtin_bit_cast(float, u); }
static __device__ __forceinline__ unsigned fcb(float f) { return __builtin_bit_cast(unsigned, f); }
static __device__ __forceinline__ float sigf(float x)   { return 1.0f / (1.0f + __expf(-x)); }
static __device__ __forceinline__ float tanhf_(float x) { return 1.0f - 2.0f / (__expf(2.0f * x) + 1.0f); }

// ---- agent-scope (device-coherent) accessors ----
static __device__ __forceinline__ unsigned ldu32(const void* p) {
    return __hip_atomic_load((const unsigned*)p, __ATOMIC_RELAXED, SC_AGENT);
}
static __device__ __forceinline__ unsigned long long ldu64(const void* p) {
    return __hip_atomic_load((const unsigned long long*)p, __ATOMIC_RELAXED, SC_AGENT);
}
static __device__ __forceinline__ void stu32(void* p, unsigned v) {
    __hip_atomic_store((unsigned*)p, v, __ATOMIC_RELAXED, SC_AGENT);
}
static __device__ __forceinline__ void stu64(void* p, unsigned long long v) {
    __hip_atomic_store((unsigned long long*)p, v, __ATOMIC_RELAXED, SC_AGENT);
}
static __device__ __forceinline__ bf16x8 ld_bf16x8_sys(const unsigned short* p) {
    union { unsigned long long q[2]; bf16x8 v; } u;
    u.q[0] = ldu64(p);
    u.q[1] = ldu64(p + 4);
    return u.v;
}
static __device__ __forceinline__ unsigned long long packbf4(float a, float b, float c, float d) {
    return (unsigned long long)f2bf(a)
         | ((unsigned long long)f2bf(b) << 16)
         | ((unsigned long long)f2bf(c) << 32)
         | ((unsigned long long)f2bf(d) << 48);
}

// ---------------- fp32 -> bf16 conversion (once per launch) ----------------
__global__ void cvt4_kernel(const float4* __restrict__ in, ushort4* __restrict__ out, int n4) {
    int i  = blockIdx.x * blockDim.x + threadIdx.x;
    int st = gridDim.x * blockDim.x;
    for (; i < n4; i += st) {
        float4 v = in[i];
        ushort4 o;
        o.x = f2bf(v.x); o.y = f2bf(v.y); o.z = f2bf(v.z); o.w = f2bf(v.w);
        out[i] = o;
    }
}

// ---------------- valid-length precompute + attS init ----------------
__global__ __launch_bounds__(256) void len_kernel(const float* __restrict__ mask,
                                                  int* __restrict__ Llen,
                                                  float* __restrict__ attS) {
    __shared__ int red[256];
    const int b = blockIdx.x, tid = threadIdx.x;
    int c = 0;
    for (int r = tid; r < RAL; r += 256) c += (mask[b * RAL + r] != 0.0f) ? 1 : 0;
    red[tid] = c;
    __syncthreads();
    for (int s = 128; s > 0; s >>= 1) {
        if (tid < s) red[tid] += red[tid + s];
        __syncthreads();
    }
    if (tid == 0) Llen[b] = red[0];
    if (tid < NSPLIT) attS[b * NSPLIT + tid] = 1.0f / NSPLIT;  // attM=0, attC=0 -> ctx=0 at t=0
}

// ---------------- shared-memory overlays ----------------
struct SmLstm {
    float zp[7][4][64][4];   // 28672 B
    float hT[16][17];        //  1088 B  (epilogue transpose for packed h stores)
};
struct SmAttn {
    float q_lds[CS];        //  1024
    float e_lds[RSPL];      //  2048
    float ctxp[32][CS];     // 32768
    float red[32];          //   128
};
static constexpr size_t SMSZ = sizeof(SmLstm) > sizeof(SmAttn) ? sizeof(SmLstm) : sizeof(SmAttn);

struct PParams {
    const void* keyp; const void* valp;
    const int* Llen; const int* y;
    const unsigned short* embb;
    const unsigned short* WihA; const unsigned short* WhhA;
    const float* bihA; const float* bhhA;
    const unsigned short* WihB; const unsigned short* WhhB;
    const float* bihB; const float* bhhB;
    const unsigned short* Wqb; const float* bq;
    const float* Wc; const float* bc;
    unsigned short* ha; unsigned short* hbuf;
    float* ca; float* cbuf;
    float* attM; float* attS; float* attC;
    float* qbuf;
    unsigned* grp; unsigned* root;
    float* outp;
};

// ---------------- hierarchical monotonic grid barrier (256 blocks = 16 groups x 16) ----
// Proven in R3 (768 crossings/launch). Monotonic counters, no reset race.
static __device__ __forceinline__ void gbar(unsigned* grp, unsigned* root, int blk, int round) {
    asm volatile("s_waitcnt vmcnt(0) lgkmcnt(0)" ::: "memory");
    __syncthreads();
    if (threadIdx.x == 0) {
        unsigned* g = grp + (blk >> 4) * 32;            // 16 groups, 128B-padded lines
        unsigned old = __hip_atomic_fetch_add(g, 1u, __ATOMIC_RELAXED, SC_AGENT);
        if (old == (unsigned)(round * 16 + 15))         // last of the group this round
            __hip_atomic_fetch_add(root, 1u, __ATOMIC_RELAXED, SC_AGENT);
        const unsigned tgt = (unsigned)((round + 1) * 16);
        while (__hip_atomic_load(root, __ATOMIC_RELAXED, SC_AGENT) < tgt)
            __builtin_amdgcn_s_sleep(8);
    }
    __syncthreads();
}

// ---------------- ctx merge: 8 bf16 elems from NSPLIT unnormalized partials ----------------
static __device__ __forceinline__ bf16x8 ctx_merge8(const float* cb, const float* wm) {
    union { unsigned short s[8]; bf16x8 v; } r;
#pragma unroll
    for (int e = 0; e < 8; e += 2) {
        float x0 = 0.f, x1 = 0.f;
#pragma unroll
        for (int s2 = 0; s2 < NSPLIT; ++s2) {
            unsigned long long q = ldu64(cb + (long)s2 * CS + e);
            x0 += wm[s2] * bcf((unsigned)q);
            x1 += wm[s2] * bcf((unsigned)(q >> 32));
        }
        r.s[e]     = f2bf(x0);
        r.s[e + 1] = f2bf(x1);
    }
    return r.v;
}

// ---------------- KV L2-warm touch (read-only; pipelined; DCE-proof) ----------------
template <bool KVBF>
static __device__ __forceinline__ void kv_touch(int blk, const void* ptr,
                                                const int* __restrict__ Llen,
                                                int rr, int rstride, int cc, int budget)
{
    if (!KVBF) return;
    const int b = blk >> 1, sp = blk & 1;
    const int L = Llen[b];
    const int rhalf = (L + 1) >> 1;
    const int rbase = sp * rhalf;
    int nv = L - rbase; if (nv > rhalf) nv = rhalf;
    if (nv > budget) nv = budget;
    const uint4* kp = (const uint4*)((const unsigned short*)ptr
                      + ((long)b * RAL + rbase) * CS) + cc;
    unsigned acc = 0;
    for (int r = rr; r < nv; r += rstride) {
        uint4 u = kp[(long)r * 32];
        acc ^= u.x ^ u.y ^ u.z ^ u.w;
    }
    asm volatile("" :: "v"(acc));   // keep loads live (no DCE)
}

// ---------------- LSTM phase: waves 0-7 active (K-split 128 wide each) ----------------
// All 16 waves of the block MUST call this (unconditional internal __syncthreads).
template <bool ISA>
static __device__ __forceinline__ void lstm_phase(
    int blk, int tid,
    const unsigned short* xrow,            // !ISA: haOut base (stride HFS)
    const float* attM, const float* attS, const float* attC,   // ISA only
    const unsigned short* embb, const int* yidx, int t,        // ISA only
    const unsigned short* hIn,             // h-state base (stride HFS), coherent
    const unsigned short* Wih, const unsigned short* Whh,
    const float* bih, const float* bhh,
    float* cst, unsigned short* hout,
    SmLstm* sm)
{
    const int lane = tid & 63;
    const int wv   = tid >> 6;      // 0..15
    const bool act = (wv < 8);
    const int quad = lane >> 4;
    const int l16  = lane & 15;
    const int jsl  = blk & 31;
    const int bgr  = blk >> 5;
    const int j    = jsl * 16 + l16;
    const int mrow = bgr * 16 + l16;

    f32x4 acc[4];
#pragma unroll
    for (int g = 0; g < 4; ++g) acc[g] = (f32x4)0.0f;

    if (act) {
        const int seg  = wv >> 1;       // 0..3
        const int sub  = wv & 1;
        const int off0 = sub * 128 + quad * 8;

        const unsigned short* arow = nullptr;
        const float* c0 = nullptr;
        float wm[NSPLIT];
        bool scA;
        if (seg >= 2) {            // h-state
            arow = hIn + (long)mrow * HFS + (seg & 1) * 256 + off0;
            scA = true;
        } else if (!ISA) {         // x = haOut row
            arow = xrow + (long)mrow * HFS + (seg & 1) * 256 + off0;
            scA = true;
        } else if (seg == 0) {     // emb gather (plain, read-only)
            arow = embb + (long)yidx[mrow * LAL + t] * EMB + off0;
            scA = false;
        } else {                   // ctx merge (NSPLIT partials)
            c0 = attC + (long)mrow * NSPLIT * CS + off0;
            float Ms[NSPLIT], Ss[NSPLIT];
#pragma unroll
            for (int s = 0; s < NSPLIT; ++s) {
                Ms[s] = bcf(ldu32(attM + mrow * NSPLIT + s));
                Ss[s] = bcf(ldu32(attS + mrow * NSPLIT + s));
            }
            float mm = Ms[0];
#pragma unroll
            for (int s = 1; s < NSPLIT; ++s) mm = fmaxf(mm, Ms[s]);
            float den = 0.f;
#pragma unroll
            for (int s = 0; s < NSPLIT; ++s) { wm[s] = __expf(Ms[s] - mm); den += wm[s] * Ss[s]; }
            float inv = 1.0f / den;
#pragma unroll
            for (int s = 0; s < NSPLIT; ++s) wm[s] *= inv;
            scA = false;
        }

        const unsigned short* wb = ((seg < 2) ? Wih : Whh) + (seg & 1) * 256 + off0;
        const unsigned short* wg[4];
#pragma unroll
        for (int g = 0; g < 4; ++g) wg[g] = wb + (long)(g * HFS + j) * HFS;

#pragma unroll
        for (int kc = 0; kc < 4; ++kc) {
            bf16x8 a;
            if (scA)                   a = ld_bf16x8_sys(arow + kc * 32);
            else if (!ISA || seg == 0) a = *(const bf16x8*)(arow + kc * 32);
            else                       a = ctx_merge8(c0 + kc * 32, wm);
            bf16x8 b0 = *(const bf16x8*)(wg[0] + kc * 32);
            bf16x8 b1 = *(const bf16x8*)(wg[1] + kc * 32);
            bf16x8 b2 = *(const bf16x8*)(wg[2] + kc * 32);
            bf16x8 b3 = *(const bf16x8*)(wg[3] + kc * 32);
            acc[0] = __builtin_amdgcn_mfma_f32_16x16x32_bf16(a, b0, acc[0], 0, 0, 0);
            acc[1] = __builtin_amdgcn_mfma_f32_16x16x32_bf16(a, b1, acc[1], 0, 0, 0);
            acc[2] = __builtin_amdgcn_mfma_f32_16x16x32_bf16(a, b2, acc[2], 0, 0, 0);
            acc[3] = __builtin_amdgcn_mfma_f32_16x16x32_bf16(a, b3, acc[3], 0, 0, 0);
        }

        if (wv != 0) {
#pragma unroll
            for (int g = 0; g < 4; ++g)
                *(f32x4*)&sm->zp[wv - 1][g][lane][0] = acc[g];
        }
    }
    __syncthreads();   // ALL 16 waves
    if (wv == 0) {
#pragma unroll
        for (int g = 0; g < 4; ++g) {
#pragma unroll
            for (int w = 0; w < 7; ++w)
                acc[g] += *(const f32x4*)&sm->zp[w][g][lane][0];
        }
        const float bI = bih[j]           + bhh[j];
        const float bF = bih[HFS + j]     + bhh[HFS + j];
        const float bG = bih[2 * HFS + j] + bhh[2 * HFS + j];
        const float bO = bih[3 * HFS + j] + bhh[3 * HFS + j];
#pragma unroll
        for (int r = 0; r < 4; ++r) {
            int m   = bgr * 16 + quad * 4 + r;  // C/D row = batch
            int idx = m * HFS + j;
            float iv = sigf(acc[0][r] + bI);
            float fv = sigf(acc[1][r] + bF);
            float gv = tanhf_(acc[2][r] + bG);
            float ov = sigf(acc[3][r] + bO);
            float cn = fv * cst[idx] + iv * gv;
            cst[idx] = cn;
            sm->hT[quad * 4 + r][l16] = ov * tanhf_(cn);
        }
        // transpose & coherent-store packed h (4 bf16 per lane); wave-internal LDS RAW
        float h0 = sm->hT[l16][quad * 4 + 0];
        float h1 = sm->hT[l16][quad * 4 + 1];
        float h2 = sm->hT[l16][quad * 4 + 2];
        float h3 = sm->hT[l16][quad * 4 + 3];
        stu64(hout + (long)(bgr * 16 + l16) * HFS + jsl * 16 + quad * 4,
              packbf4(h0, h1, h2, h3));
    }
}

// ---------------- q-GEMM phase: q = hb @ Wq^T + bq, blocks 0..127, waves 0-7 ----------------
// Wq read ONCE device-wide per step (was 256 KB per attn block = 64 MB/step).
// All 16 waves of blocks 0..127 must call (internal __syncthreads).
static __device__ __forceinline__ void qcalc_phase(
    int blk, int tid,
    const unsigned short* hb,               // hbOut(t), coherent
    const unsigned short* Wqb, const float* bq,
    float* qbuf, SmLstm* sm)
{
    const int lane = tid & 63;
    const int wv   = tid >> 6;
    const bool act = (wv < 8);
    const int quad = lane >> 4;
    const int l16  = lane & 15;
    const int mt   = blk >> 4;      // 0..7
    const int nt   = blk & 15;      // 0..15

    f32x4 acc = (f32x4)0.0f;
    if (act) {
        const int mrow = mt * 16 + l16;
        const int c    = nt * 16 + l16;
        const int koff = wv * 64 + quad * 8;
        const unsigned short* ar = hb  + (long)mrow * HFS + koff;
        const unsigned short* br = Wqb + (long)c    * HFS + koff;
#pragma unroll
        for (int kc = 0; kc < 2; ++kc) {
            bf16x8 a = ld_bf16x8_sys(ar + kc * 32);
            bf16x8 b = *(const bf16x8*)(br + kc * 32);
            acc = __builtin_amdgcn_mfma_f32_16x16x32_bf16(a, b, acc, 0, 0, 0);
        }
        if (wv != 0) *(f32x4*)&sm->zp[wv - 1][0][lane][0] = acc;
    }
    __syncthreads();
    if (wv == 0) {
#pragma unroll
        for (int w = 0; w < 7; ++w) acc += *(const f32x4*)&sm->zp[w][0][lane][0];
        const int c = nt * 16 + l16;
        const float bqv = bq[c];
#pragma unroll
        for (int r = 0; r < 4; ++r) {
            int b2 = mt * 16 + quad * 4 + r;
            stu32(qbuf + (long)b2 * CS + c, fcb(acc[r] + bqv));
        }
    }
}

// ---------------- attention partial phase (block = (b, sp), all 1024 threads) ----------------
template <bool KVBF>
static __device__ __forceinline__ void attn_phase(
    int blk, int tid,
    const void* keyp, const void* valp,
    const int* __restrict__ Llen,
    const float* __restrict__ qbuf,
    float* __restrict__ attM, float* __restrict__ attS, float* __restrict__ attC,
    SmAttn* sm)
{
    const int b     = blk >> 1;
    const int sp    = blk & 1;
    const int L     = Llen[b];
    const int rhalf = (L + 1) >> 1;               // balanced split boundary
    const int rbase = sp * rhalf;
    int nv = L - rbase;
    if (nv > rhalf) nv = rhalf;

    if (nv <= 0) {   // block-uniform; unreachable for L>=512, kept for safety
        if (tid < CS) stu32(attC + ((long)b * NSPLIT + sp) * CS + tid, fcb(0.0f));
        if (tid == 0) {
            stu32(attM + b * NSPLIT + sp, fcb(-1e30f));
            stu32(attS + b * NSPLIT + sp, fcb(0.0f));
        }
        return;
    }

    if (tid < CS) sm->q_lds[tid] = bcf(ldu32(qbuf + (long)b * CS + tid));
    __syncthreads();

    // energy: 4 threads per row (64 contiguous channels each), 256 rows per pass
    {
        const int jj   = tid & 3;
        const int rloc = tid >> 2;      // 0..255
        for (int r0 = 0; r0 < nv; r0 += 256) {
            const int r = r0 + rloc;
            float acc = 0.0f;
            if (r < nv) {
                if (KVBF) {
                    const unsigned short* kp = (const unsigned short*)keyp
                        + ((long)b * RAL + rbase + r) * CS + jj * 64;
#pragma unroll
                    for (int i = 0; i < 8; ++i) {
                        uint4 u = *(const uint4*)(kp + i * 8);
                        const float* qp = &sm->q_lds[jj * 64 + i * 8];
                        float4 qa  = *(const float4*)qp;
                        float4 qb2 = *(const float4*)(qp + 4);
                        acc += bflo(u.x) * qa.x  + bfhi(u.x) * qa.y
                             + bflo(u.y) * qa.z  + bfhi(u.y) * qa.w
                             + bflo(u.z) * qb2.x + bfhi(u.z) * qb2.y
                             + bflo(u.w) * qb2.z + bfhi(u.w) * qb2.w;
                    }
                } else {
                    const float* kp = (const float*)keyp
                        + ((long)b * RAL + rbase + r) * CS + jj * 64;
#pragma unroll
                    for (int i = 0; i < 16; ++i) {
                        float4 kv = *(const float4*)(kp + i * 4);
                        float4 qa = *(const float4*)&sm->q_lds[jj * 64 + i * 4];
                        acc += kv.x * qa.x + kv.y * qa.y + kv.z * qa.z + kv.w * qa.w;
                    }
                }
            }
            acc += __shfl_xor(acc, 1);
            acc += __shfl_xor(acc, 2);
            if (jj == 0 && r < nv) sm->e_lds[r] = acc;
        }
    }
    __syncthreads();

    // local softmax stats (nv <= 512, one row per thread; 16-wave reduce)
    float pm = (tid < nv) ? sm->e_lds[tid] : -1e30f;
#pragma unroll
    for (int s = 32; s > 0; s >>= 1) pm = fmaxf(pm, __shfl_xor(pm, s));
    if ((tid & 63) == 0) sm->red[tid >> 6] = pm;
    __syncthreads();
    float M = sm->red[0];
#pragma unroll
    for (int i = 1; i < 16; ++i) M = fmaxf(M, sm->red[i]);

    float ps = 0.0f;
    if (tid < nv) { float v = __expf(sm->e_lds[tid] - M); sm->e_lds[tid] = v; ps = v; }
#pragma unroll
    for (int s = 32; s > 0; s >>= 1) ps += __shfl_xor(ps, s);
    if ((tid & 63) == 0) sm->red[16 + (tid >> 6)] = ps;
    __syncthreads();
    float S = 0.0f;
#pragma unroll
    for (int i = 0; i < 16; ++i) S += sm->red[16 + i];

    if (tid == 0) {
        stu32(attM + b * NSPLIT + sp, fcb(M));
        stu32(attS + b * NSPLIT + sp, fcb(S));
    }

    // partial context (unnormalized): 32 row-groups, lane owns 8 contiguous channels (16B loads)
    {
        const int rg = tid >> 5;         // 0..31
        const int c8 = (tid & 31) * 8;   // 0..248
        float a0=0.f,a1=0.f,a2=0.f,a3=0.f,a4=0.f,a5=0.f,a6=0.f,a7=0.f;
        if (KVBF) {
            const unsigned short* vb = (const unsigned short*)valp
                + ((long)b * RAL + rbase) * CS + c8;
            int r = rg;
            for (; r + 224 < nv; r += 256) {          // 8-deep
                uint4 u[8]; float w[8];
#pragma unroll
                for (int k = 0; k < 8; ++k) u[k] = *(const uint4*)(vb + (long)(r + 32 * k) * CS);
#pragma unroll
                for (int k = 0; k < 8; ++k) w[k] = sm->e_lds[r + 32 * k];
#pragma unroll
                for (int k = 0; k < 8; ++k) {
                    a0 += w[k] * bflo(u[k].x); a1 += w[k] * bfhi(u[k].x);
                    a2 += w[k] * bflo(u[k].y); a3 += w[k] * bfhi(u[k].y);
                    a4 += w[k] * bflo(u[k].z); a5 += w[k] * bfhi(u[k].z);
                    a6 += w[k] * bflo(u[k].w); a7 += w[k] * bfhi(u[k].w);
                }
            }
            for (; r + 96 < nv; r += 128) {           // 4-deep
                uint4 u[4]; float w[4];
#pragma unroll
                for (int k = 0; k < 4; ++k) u[k] = *(const uint4*)(vb + (long)(r + 32 * k) * CS);
#pragma unroll
                for (int k = 0; k < 4; ++k) w[k] = sm->e_lds[r + 32 * k];
#pragma unroll
                for (int k = 0; k < 4; ++k) {
                    a0 += w[k] * bflo(u[k].x); a1 += w[k] * bfhi(u[k].x);
                    a2 += w[k] * bflo(u[k].y); a3 += w[k] * bfhi(u[k].y);
                    a4 += w[k] * bflo(u[k].z); a5 += w[k] * bfhi(u[k].z);
                    a6 += w[k] * bflo(u[k].w); a7 += w[k] * bfhi(u[k].w);
                }
            }
            for (; r < nv; r += 32) {
                uint4 u = *(const uint4*)(vb + (long)r * CS);
                float w = sm->e_lds[r];
                a0 += w * bflo(u.x); a1 += w * bfhi(u.x);
                a2 += w * bflo(u.y); a3 += w * bfhi(u.y);
                a4 += w * bflo(u.z); a5 += w * bfhi(u.z);
                a6 += w * bflo(u.w); a7 += w * bfhi(u.w);
            }
        } else {
            const float* vb = (const float*)valp + ((long)b * RAL + rbase) * CS + c8;
            int r = rg;
            for (; r + 96 < nv; r += 128) {
                float4 v0[4], v1[4]; float w[4];
#pragma unroll
                for (int k = 0; k < 4; ++k) {
                    v0[k] = *(const float4*)(vb + (long)(r + 32 * k) * CS);
                    v1[k] = *(const float4*)(vb + (long)(r + 32 * k) * CS + 4);
                }
#pragma unroll
                for (int k = 0; k < 4; ++k) w[k] = sm->e_lds[r + 32 * k];
#pragma unroll
                for (int k = 0; k < 4; ++k) {
                    a0 += w[k] * v0[k].x; a1 += w[k] * v0[k].y;
                    a2 += w[k] * v0[k].z; a3 += w[k] * v0[k].w;
                    a4 += w[k] * v1[k].x; a5 += w[k] * v1[k].y;
                    a6 += w[k] * v1[k].z; a7 += w[k] * v1[k].w;
                }
            }
            for (; r < nv; r += 32) {
                float4 v0 = *(const float4*)(vb + (long)r * CS);
                float4 v1 = *(const float4*)(vb + (long)r * CS + 4);
                float w = sm->e_lds[r];
                a0 += w * v0.x; a1 += w * v0.y; a2 += w * v0.z; a3 += w * v0.w;
                a4 += w * v1.x; a5 += w * v1.y; a6 += w * v1.z; a7 += w * v1.w;
            }
        }
        float4 o0 = {a0, a1, a2, a3};
        float4 o1 = {a4, a5, a6, a7};
        *(float4*)&sm->ctxp[rg][c8]     = o0;
        *(float4*)&sm->ctxp[rg][c8 + 4] = o1;
    }
    __syncthreads();

    if (tid < CS) {
        float cv = 0.0f;
#pragma unroll
        for (int g = 0; g < 32; ++g) cv += sm->ctxp[g][tid];
        stu32(attC + ((long)b * NSPLIT + sp) * CS + tid, fcb(cv));   // unnormalized
    }
}

// ---------------- logits: 512-thread span; block = (16-batch, 1-2 vocab) slice ----------------
static __device__ __forceinline__ void logits_phase(
    int blk, int tid,   // tid in [0,512)
    const unsigned short* __restrict__ hb,
    const float* __restrict__ attM, const float* __restrict__ attS,
    const float* __restrict__ attC,
    const float* __restrict__ Wc, const float* __restrict__ bc,
    float* __restrict__ outp, int tOut)
{
    const int bgr  = blk >> 5;        // 0..7
    const int vsl  = blk & 31;        // 0..31
    const int bloc = tid >> 5;        // 0..15
    const int jj   = tid & 31;        // 0..31
    const int b    = bgr * 16 + bloc;

    float Ms[NSPLIT], Ss[NSPLIT], wgt[NSPLIT];
#pragma unroll
    for (int s = 0; s < NSPLIT; ++s) {
        Ms[s] = bcf(ldu32(attM + b * NSPLIT + s));
        Ss[s] = bcf(ldu32(attS + b * NSPLIT + s));
    }
    float mm = Ms[0];
#pragma unroll
    for (int s = 1; s < NSPLIT; ++s) mm = fmaxf(mm, Ms[s]);
    float den = 0.f;
#pragma unroll
    for (int s = 0; s < NSPLIT; ++s) { wgt[s] = __expf(Ms[s] - mm); den += wgt[s] * Ss[s]; }
    float inv = 1.0f / den;
#pragma unroll
    for (int s = 0; s < NSPLIT; ++s) wgt[s] *= inv;

    float xh[16];
    const unsigned short* hp = hb + (long)b * HFS + jj * 16;
#pragma unroll
    for (int g = 0; g < 4; ++g) {
        unsigned long long q = ldu64(hp + g * 4);
        xh[g * 4 + 0] = bflo((unsigned)( q        & 0xffffu));
        xh[g * 4 + 1] = bflo((unsigned)((q >> 16) & 0xffffu));
        xh[g * 4 + 2] = bflo((unsigned)((q >> 32) & 0xffffu));
        xh[g * 4 + 3] = bflo((unsigned)((q >> 48) & 0xffffu));
    }
    float xc[8];
    const float* cb = attC + (long)b * NSPLIT * CS + jj * 8;
#pragma unroll
    for (int g = 0; g < 4; ++g) {
        float x0 = 0.f, x1 = 0.f;
#pragma unroll
        for (int s = 0; s < NSPLIT; ++s) {
            unsigned long long q = ldu64(cb + (long)s * CS + g * 2);
            x0 += wgt[s] * bcf((unsigned)q);
            x1 += wgt[s] * bcf((unsigned)(q >> 32));
        }
        xc[g * 2]     = x0;
        xc[g * 2 + 1] = x1;
    }

#pragma unroll
    for (int vv = 0; vv < 2; ++vv) {
        int v = vsl + vv * 32;
        if (v >= VOC) break;
        const float* wr = Wc + (long)v * (HFS + CS);
        float part = 0.0f;
#pragma unroll
        for (int g = 0; g < 4; ++g) {
            float4 wv4 = *(const float4*)(wr + jj * 16 + g * 4);
            part += wv4.x * xh[g * 4 + 0] + wv4.y * xh[g * 4 + 1]
                  + wv4.z * xh[g * 4 + 2] + wv4.w * xh[g * 4 + 3];
        }
#pragma unroll
        for (int g = 0; g < 2; ++g) {
            float4 wv4 = *(const float4*)(wr + HFS + jj * 8 + g * 4);
            part += wv4.x * xc[g * 4 + 0] + wv4.y * xc[g * 4 + 1]
                  + wv4.z * xc[g * 4 + 2] + wv4.w * xc[g * 4 + 3];
        }
        part += __shfl_xor(part, 1);
        part += __shfl_xor(part, 2);
        part += __shfl_xor(part, 4);
        part += __shfl_xor(part, 8);
        part += __shfl_xor(part, 16);
        if (jj == 0)
            outp[((long)b * LAL + tOut) * VOC + v] = part + bc[v];
    }
}

// ---------------- fused kernel: 256 blocks x 1024 threads, 4 barriers/step ----------------
template <bool KVBF>
__global__ __launch_bounds__(1024, 4) void fused_kernel(PParams P)
{
    __shared__ __align__(16) unsigned char smraw[SMSZ];
    SmLstm* smL = (SmLstm*)smraw;
    SmAttn* smA = (SmAttn*)smraw;

    const int blk = blockIdx.x;
    const int tid = threadIdx.x;
    const int wv  = tid >> 6;
    int round = 0;

    for (int t = 0; t < LAL; ++t) {
        const unsigned short* haIn  = P.ha   + (t & 1) * (BS * HFS);
        unsigned short*       haOut = P.ha   + ((t + 1) & 1) * (BS * HFS);
        const unsigned short* hbIn  = P.hbuf + (t & 1) * (BS * HFS);
        unsigned short*       hbOut = P.hbuf + ((t + 1) & 1) * (BS * HFS);

        // phase 1: LSTM A (waves 0-7); waves 8-15 warm key slice into this XCD's L2
        if (wv >= 8)
            kv_touch<KVBF>(blk, P.keyp, P.Llen, (tid - 512) >> 5, 16, (tid - 512) & 31, 160);
        lstm_phase<true>(blk, tid, nullptr, P.attM, P.attS, P.attC,
                         P.embb, P.y, t, haIn,
                         P.WihA, P.WhhA, P.bihA, P.bhhA, P.ca, haOut, smL);
        gbar(P.grp, P.root, blk, round++);

        // phase 2: LSTM B (waves 0-7) CONCURRENT with logits(t-1) (waves 8-15)
        if (wv >= 8 && t > 0)
            logits_phase(blk, tid - 512, hbIn, P.attM, P.attS, P.attC,
                         P.Wc, P.bc, P.outp, t - 1);
        lstm_phase<false>(blk, tid, haOut, nullptr, nullptr, nullptr,
                          nullptr, nullptr, t, hbIn,
                          P.WihB, P.WhhB, P.bihB, P.bhhB, P.cbuf, hbOut, smL);
        gbar(P.grp, P.root, blk, round++);

        // phase 3: q-GEMM (blocks 0-127, waves 0-7); everyone else warms val slice
        if (blk < 128) {
            if (wv >= 8)
                kv_touch<KVBF>(blk, P.valp, P.Llen, (tid - 512) >> 5, 16, (tid - 512) & 31, 64);
            qcalc_phase(blk, tid, hbOut, P.Wqb, P.bq, P.qbuf, smL);
        } else {
            kv_touch<KVBF>(blk, P.valp, P.Llen, tid >> 5, 32, tid & 31, 128);
        }
        gbar(P.grp, P.root, blk, round++);

        // phase 4: attention partials (all 16 waves)
        attn_phase<KVBF>(blk, tid, P.keyp, P.valp, P.Llen,
                         P.qbuf, P.attM, P.attS, P.attC, smA);
        gbar(P.grp, P.root, blk, round++);
    }
    // final logits (t = LAL-1); hb(LAL-1) lives in hbuf[LAL & 1] == hbuf[0]
    if (tid < 512)
        logits_phase(blk, tid, P.hbuf + (LAL & 1) * (BS * HFS),
                     P.attM, P.attS, P.attC, P.Wc, P.bc, P.outp, LAL - 1);
}

// ---------------- host ----------------
extern "C" void kernel_launch(void* const* d_in, const int* in_sizes, int n_in,
                              void* d_out, int out_size, void* d_ws, size_t ws_size,
                              hipStream_t stream)
{
    (void)in_sizes; (void)n_in; (void)out_size;
    const float* keyf  = (const float*)d_in[0];
    const float* valf  = (const float*)d_in[1];
    const float* mask  = (const float*)d_in[2];
    const float* embf  = (const float*)d_in[3];
    const float* WihAf = (const float*)d_in[4];
    const float* WhhAf = (const float*)d_in[5];
    const float* bihA  = (const float*)d_in[6];
    const float* bhhA  = (const float*)d_in[7];
    const float* WihBf = (const float*)d_in[8];
    const float* WhhBf = (const float*)d_in[9];
    const float* bihB  = (const float*)d_in[10];
    const float* bhhB  = (const float*)d_in[11];
    const float* Wqf   = (const float*)d_in[12];
    const float* bq    = (const float*)d_in[13];
    const float* Wc    = (const float*)d_in[14];
    const float* bc    = (const float*)d_in[15];
    const int*   y     = (const int*)d_in[16];
    float* outp = (float*)d_out;

    size_t off = 0;
    auto take = [&](size_t bytes) -> void* {
        void* p = (char*)d_ws + off;
        off += (bytes + 255) & ~(size_t)255;
        return p;
    };

    // ---- zero-initialized state block (memset every launch; includes barrier counters) ----
    unsigned short* ha    = (unsigned short*)take((size_t)2 * BS * HFS * 2); // double-buffered
    unsigned short* hbuf  = (unsigned short*)take((size_t)2 * BS * HFS * 2); // double-buffered
    float*          ca    = (float*)take((size_t)BS * HFS * 4);
    float*          cbuf  = (float*)take((size_t)BS * HFS * 4);
    float*          attM  = (float*)take((size_t)BS * NSPLIT * 4);
    float*          attS  = (float*)take((size_t)BS * NSPLIT * 4);
    float*          attC  = (float*)take((size_t)BS * NSPLIT * CS * 4);
    float*          qbuf  = (float*)take((size_t)BS * CS * 4);
    unsigned*       grp   = (unsigned*)take((size_t)16 * 32 * 4);   // padded group counters
    unsigned*       root  = (unsigned*)take((size_t)32 * 4);
    size_t stateBytes = off;

    int*            Llen  = (int*)take((size_t)BS * 4);
    unsigned short* embb  = (unsigned short*)take((size_t)VOC * EMB * 2);
    unsigned short* WihAb = (unsigned short*)take((size_t)4 * HFS * HFS * 2);
    unsigned short* WhhAb = (unsigned short*)take((size_t)4 * HFS * HFS * 2);
    unsigned short* WihBb = (unsigned short*)take((size_t)4 * HFS * HFS * 2);
    unsigned short* WhhBb = (unsigned short*)take((size_t)4 * HFS * HFS * 2);
    unsigned short* Wqb   = (unsigned short*)take((size_t)CS * HFS * 2);

    // --- KV bf16 tiers ---
    const size_t kvBytes = (size_t)BS * RAL * CS * 2;  // 67 MB each
    unsigned short* keyb = nullptr;
    unsigned short* valb = nullptr;
    bool kvbf = false;
    bool keyInVal = false;
    if (off + 2 * (kvBytes + 256) <= ws_size) {
        keyb = (unsigned short*)take(kvBytes);
        valb = (unsigned short*)take(kvBytes);
        kvbf = true;
    } else if (off + kvBytes + 256 <= ws_size) {
        valb = (unsigned short*)take(kvBytes);
        keyb = (unsigned short*)d_in[1];
        kvbf = true;
        keyInVal = true;
    }

    hipMemsetAsync(d_ws, 0, stateBytes, stream);
    len_kernel<<<dim3(BS), dim3(256), 0, stream>>>(mask, Llen, attS);

    auto cvt = [&](const float* src, unsigned short* dst, long n) {
        int n4 = (int)(n / 4);
        int blocks = (n4 + 255) / 256;
        if (blocks > 8192) blocks = 8192;
        cvt4_kernel<<<dim3(blocks), dim3(256), 0, stream>>>((const float4*)src, (ushort4*)dst, n4);
    };
    cvt(embf,  embb,  (long)VOC * EMB);
    cvt(WihAf, WihAb, (long)4 * HFS * HFS);
    cvt(WhhAf, WhhAb, (long)4 * HFS * HFS);
    cvt(WihBf, WihBb, (long)4 * HFS * HFS);
    cvt(WhhBf, WhhBb, (long)4 * HFS * HFS);
    cvt(Wqf,   Wqb,   (long)CS * HFS);
    if (kvbf) {
        if (keyInVal) {
            cvt(valf, valb, (long)BS * RAL * CS);   // must finish before key overwrites d_in[1]
            cvt(keyf, keyb, (long)BS * RAL * CS);
        } else {
            cvt(keyf, keyb, (long)BS * RAL * CS);
            cvt(valf, valb, (long)BS * RAL * CS);
        }
    }

    PParams prm;
    prm.keyp = kvbf ? (const void*)keyb : (const void*)keyf;
    prm.valp = kvbf ? (const void*)valb : (const void*)valf;
    prm.Llen = Llen; prm.y = y;
    prm.embb = embb;
    prm.WihA = WihAb; prm.WhhA = WhhAb; prm.bihA = bihA; prm.bhhA = bhhA;
    prm.WihB = WihBb; prm.WhhB = WhhBb; prm.bihB = bihB; prm.bhhB = bhhB;
    prm.Wqb = Wqb; prm.bq = bq; prm.Wc = Wc; prm.bc = bc;
    prm.ha = ha; prm.hbuf = hbuf; prm.ca = ca; prm.cbuf = cbuf;
    prm.attM = attM; prm.attS = attS; prm.attC = attC;
    prm.qbuf = qbuf;
    prm.grp = grp; prm.root = root;
    prm.outp = outp;

    void* kargs[] = { &prm };
    if (kvbf)
        hipLaunchCooperativeKernel(reinterpret_cast<void*>(&fused_kernel<true>),
                                   dim3(NBLK), dim3(1024), kargs, 0, stream);
    else
        hipLaunchCooperativeKernel(reinterpret_cast<void*>(&fused_kernel<false>),
                                   dim3(NBLK), dim3(1024), kargs, 0, stream);
}

// Round 6
// 15993.874 us; speedup vs baseline: 1.1045x; 1.1045x over previous
//
#include <hip/hip_runtime.h>
#include <cstdint>
#include <cstddef>

static constexpr int BS  = 128;
static constexpr int RAL = 1024;
static constexpr int LAL = 256;
static constexpr int CS  = 256;
static constexpr int VOC = 34;
static constexpr int HFS = 512;
static constexpr int EMB = 256;

static constexpr int NSPLIT = 2;
static constexpr int RSPL   = RAL / NSPLIT;   // 512 max rows per split block
static constexpr int NBLK   = 256;            // proven co-resident

typedef float  f32x4  __attribute__((ext_vector_type(4)));
typedef short  bf16x8 __attribute__((ext_vector_type(8)));

#define SC_AGENT __HIP_MEMORY_SCOPE_AGENT

static __device__ __forceinline__ float bflo(unsigned int u) {
    return __builtin_bit_cast(float, u << 16);
}
static __device__ __forceinline__ float bfhi(unsigned int u) {
    return __builtin_bit_cast(float, u & 0xffff0000u);
}
static __device__ __forceinline__ unsigned short f2bf(float f) {
    unsigned int x = __builtin_bit_cast(unsigned int, f);
    x = (x + 0x7fffu + ((x >> 16) & 1u)) >> 16;   // RNE
    return (unsigned short)x;
}
static __device__ __forceinline__ float bcf(unsigned u) { return __builtin_bit_cast(float, u); }
static __device__ __forceinline__ unsigned fcb(float f) { return __builtin_bit_cast(unsigned, f); }
static __device__ __forceinline__ float sigf(float x)   { return 1.0f / (1.0f + __expf(-x)); }
static __device__ __forceinline__ float tanhf_(float x) { return 1.0f - 2.0f / (__expf(2.0f * x) + 1.0f); }

// ---- agent-scope (device-coherent) accessors ----
static __device__ __forceinline__ unsigned ldu32(const void* p) {
    return __hip_atomic_load((const unsigned*)p, __ATOMIC_RELAXED, SC_AGENT);
}
static __device__ __forceinline__ unsigned long long ldu64(const void* p) {
    return __hip_atomic_load((const unsigned long long*)p, __ATOMIC_RELAXED, SC_AGENT);
}
static __device__ __forceinline__ void stu32(void* p, unsigned v) {
    __hip_atomic_store((unsigned*)p, v, __ATOMIC_RELAXED, SC_AGENT);
}
static __device__ __forceinline__ void stu64(void* p, unsigned long long v) {
    __hip_atomic_store((unsigned long long*)p, v, __ATOMIC_RELAXED, SC_AGENT);
}
static __device__ __forceinline__ bf16x8 ld_bf16x8_sys(const unsigned short* p) {
    union { unsigned long long q[2]; bf16x8 v; } u;
    u.q[0] = ldu64(p);
    u.q[1] = ldu64(p + 4);
    return u.v;
}
static __device__ __forceinline__ unsigned long long packbf4(float a, float b, float c, float d) {
    return (unsigned long long)f2bf(a)
         | ((unsigned long long)f2bf(b) << 16)
         | ((unsigned long long)f2bf(c) << 32)
         | ((unsigned long long)f2bf(d) << 48);
}
// int8 unpack helpers
static __device__ __forceinline__ float i8f(unsigned w) {
    return (float)(signed char)(w & 0xffu);
}
static __device__ __forceinline__ float dot4i8(unsigned w, const float* q) {
    return i8f(w) * q[0] + i8f(w >> 8) * q[1] + i8f(w >> 16) * q[2] + i8f(w >> 24) * q[3];
}

// ---------------- fp32 -> bf16 conversion (once per launch, weights only) ----------------
__global__ void cvt4_kernel(const float4* __restrict__ in, ushort4* __restrict__ out, int n4) {
    int i  = blockIdx.x * blockDim.x + threadIdx.x;
    int st = gridDim.x * blockDim.x;
    for (; i < n4; i += st) {
        float4 v = in[i];
        ushort4 o;
        o.x = f2bf(v.x); o.y = f2bf(v.y); o.z = f2bf(v.z); o.w = f2bf(v.w);
        out[i] = o;
    }
}

// ---------------- fp32 -> int8 per-row quantization (once per launch, KV) ----------------
// one 256-float row per wave; 4 rows per 256-thread block
__global__ __launch_bounds__(256) void quant8_kernel(const float* __restrict__ in,
                                                     signed char* __restrict__ out,
                                                     float* __restrict__ scale, int nrows) {
    const int row  = blockIdx.x * 4 + (threadIdx.x >> 6);
    const int lane = threadIdx.x & 63;
    if (row >= nrows) return;
    const float* rp = in + (long)row * CS;
    float4 v = *(const float4*)(rp + lane * 4);
    float m = fmaxf(fmaxf(fabsf(v.x), fabsf(v.y)), fmaxf(fabsf(v.z), fabsf(v.w)));
#pragma unroll
    for (int s = 32; s > 0; s >>= 1) m = fmaxf(m, __shfl_xor(m, s));
    const float inv = (m > 0.0f) ? 127.0f / m : 0.0f;
    unsigned a = (unsigned)((int)rintf(v.x * inv)) & 0xffu;
    unsigned b = (unsigned)((int)rintf(v.y * inv)) & 0xffu;
    unsigned c = (unsigned)((int)rintf(v.z * inv)) & 0xffu;
    unsigned d = (unsigned)((int)rintf(v.w * inv)) & 0xffu;
    *(unsigned*)(out + (long)row * CS + lane * 4) = a | (b << 8) | (c << 16) | (d << 24);
    if (lane == 0) scale[row] = (m > 0.0f) ? m / 127.0f : 0.0f;
}

// ---------------- valid-length precompute + attS init ----------------
__global__ __launch_bounds__(256) void len_kernel(const float* __restrict__ mask,
                                                  int* __restrict__ Llen,
                                                  float* __restrict__ attS) {
    __shared__ int red[256];
    const int b = blockIdx.x, tid = threadIdx.x;
    int c = 0;
    for (int r = tid; r < RAL; r += 256) c += (mask[b * RAL + r] != 0.0f) ? 1 : 0;
    red[tid] = c;
    __syncthreads();
    for (int s = 128; s > 0; s >>= 1) {
        if (tid < s) red[tid] += red[tid + s];
        __syncthreads();
    }
    if (tid == 0) Llen[b] = red[0];
    if (tid < NSPLIT) attS[b * NSPLIT + tid] = 1.0f / NSPLIT;  // attM=0, attC=0 -> ctx=0 at t=0
}

// ---------------- shared-memory overlays ----------------
struct SmLstm {
    float zp[7][4][64][4];   // 28672 B
    float hT[16][17];        //  1088 B  (epilogue transpose for packed h stores)
};
struct SmAttn {
    float hb_l[HFS];        //  2048
    float q_lds[CS];        //  1024
    float e_lds[RSPL];      //  2048
    float ctxp[32][CS];     // 32768
    float red[32];          //   128
};
static constexpr size_t SMSZ = sizeof(SmLstm) > sizeof(SmAttn) ? sizeof(SmLstm) : sizeof(SmAttn);

struct PParams {
    const void* keyp; const void* valp;          // int8 (KVQ) or f32
    const float* kscale; const float* vscale;    // per-row scales (KVQ)
    const int* Llen; const int* y;
    const unsigned short* embb;
    const unsigned short* WihA; const unsigned short* WhhA;
    const float* bihA; const float* bhhA;
    const unsigned short* WihB; const unsigned short* WhhB;
    const float* bihB; const float* bhhB;
    const unsigned short* Wqb; const float* bq;
    const float* Wc; const float* bc;
    unsigned short* ha; unsigned short* hbuf;
    float* ca; float* cbuf;
    float* attM; float* attS; float* attC;
    unsigned* grp; unsigned* root;
    float* outp;
};

// ---------------- hierarchical monotonic grid barrier (256 blocks = 16 groups x 16) ----
static __device__ __forceinline__ void gbar(unsigned* grp, unsigned* root, int blk, int round) {
    asm volatile("s_waitcnt vmcnt(0) lgkmcnt(0)" ::: "memory");
    __syncthreads();
    if (threadIdx.x == 0) {
        unsigned* g = grp + (blk >> 4) * 32;            // 16 groups, 128B-padded lines
        unsigned old = __hip_atomic_fetch_add(g, 1u, __ATOMIC_RELAXED, SC_AGENT);
        if (old == (unsigned)(round * 16 + 15))         // last of the group this round
            __hip_atomic_fetch_add(root, 1u, __ATOMIC_RELAXED, SC_AGENT);
        const unsigned tgt = (unsigned)((round + 1) * 16);
        while (__hip_atomic_load(root, __ATOMIC_RELAXED, SC_AGENT) < tgt)
            __builtin_amdgcn_s_sleep(2);
    }
    __syncthreads();
}

// ---------------- ctx merge: 8 bf16 elems from NSPLIT unnormalized partials ----------------
static __device__ __forceinline__ bf16x8 ctx_merge8(const float* cb, const float* wm) {
    union { unsigned short s[8]; bf16x8 v; } r;
#pragma unroll
    for (int e = 0; e < 8; e += 2) {
        float x0 = 0.f, x1 = 0.f;
#pragma unroll
        for (int s2 = 0; s2 < NSPLIT; ++s2) {
            unsigned long long q = ldu64(cb + (long)s2 * CS + e);
            x0 += wm[s2] * bcf((unsigned)q);
            x1 += wm[s2] * bcf((unsigned)(q >> 32));
        }
        r.s[e]     = f2bf(x0);
        r.s[e + 1] = f2bf(x1);
    }
    return r.v;
}

// ---------------- LSTM phase: waves 0-7 active (K-split 128 wide each) ----------------
// All 16 waves of the block MUST call this (unconditional internal __syncthreads).
template <bool ISA>
static __device__ __forceinline__ void lstm_phase(
    int blk, int tid,
    const unsigned short* xrow,            // !ISA: haOut base (stride HFS)
    const float* attM, const float* attS, const float* attC,   // ISA only
    const unsigned short* embb, const int* yidx, int t,        // ISA only
    const unsigned short* hIn,             // h-state base (stride HFS), coherent
    const unsigned short* Wih, const unsigned short* Whh,
    const float* bih, const float* bhh,
    float* cst, unsigned short* hout,
    SmLstm* sm)
{
    const int lane = tid & 63;
    const int wv   = tid >> 6;      // 0..15
    const bool act = (wv < 8);
    const int quad = lane >> 4;
    const int l16  = lane & 15;
    const int jsl  = blk & 31;
    const int bgr  = blk >> 5;
    const int j    = jsl * 16 + l16;
    const int mrow = bgr * 16 + l16;

    f32x4 acc[4];
#pragma unroll
    for (int g = 0; g < 4; ++g) acc[g] = (f32x4)0.0f;

    if (act) {
        const int seg  = wv >> 1;       // 0..3
        const int sub  = wv & 1;
        const int off0 = sub * 128 + quad * 8;

        const unsigned short* arow = nullptr;
        const float* c0 = nullptr;
        float wm[NSPLIT];
        bool scA;
        if (seg >= 2) {            // h-state
            arow = hIn + (long)mrow * HFS + (seg & 1) * 256 + off0;
            scA = true;
        } else if (!ISA) {         // x = haOut row
            arow = xrow + (long)mrow * HFS + (seg & 1) * 256 + off0;
            scA = true;
        } else if (seg == 0) {     // emb gather (plain, read-only)
            arow = embb + (long)yidx[mrow * LAL + t] * EMB + off0;
            scA = false;
        } else {                   // ctx merge (NSPLIT partials)
            c0 = attC + (long)mrow * NSPLIT * CS + off0;
            float Ms[NSPLIT], Ss[NSPLIT];
#pragma unroll
            for (int s = 0; s < NSPLIT; ++s) {
                Ms[s] = bcf(ldu32(attM + mrow * NSPLIT + s));
                Ss[s] = bcf(ldu32(attS + mrow * NSPLIT + s));
            }
            float mm = Ms[0];
#pragma unroll
            for (int s = 1; s < NSPLIT; ++s) mm = fmaxf(mm, Ms[s]);
            float den = 0.f;
#pragma unroll
            for (int s = 0; s < NSPLIT; ++s) { wm[s] = __expf(Ms[s] - mm); den += wm[s] * Ss[s]; }
            float inv = 1.0f / den;
#pragma unroll
            for (int s = 0; s < NSPLIT; ++s) wm[s] *= inv;
            scA = false;
        }

        const unsigned short* wb = ((seg < 2) ? Wih : Whh) + (seg & 1) * 256 + off0;
        const unsigned short* wg[4];
#pragma unroll
        for (int g = 0; g < 4; ++g) wg[g] = wb + (long)(g * HFS + j) * HFS;

#pragma unroll
        for (int kc = 0; kc < 4; ++kc) {
            bf16x8 a;
            if (scA)                   a = ld_bf16x8_sys(arow + kc * 32);
            else if (!ISA || seg == 0) a = *(const bf16x8*)(arow + kc * 32);
            else                       a = ctx_merge8(c0 + kc * 32, wm);
            bf16x8 b0 = *(const bf16x8*)(wg[0] + kc * 32);
            bf16x8 b1 = *(const bf16x8*)(wg[1] + kc * 32);
            bf16x8 b2 = *(const bf16x8*)(wg[2] + kc * 32);
            bf16x8 b3 = *(const bf16x8*)(wg[3] + kc * 32);
            acc[0] = __builtin_amdgcn_mfma_f32_16x16x32_bf16(a, b0, acc[0], 0, 0, 0);
            acc[1] = __builtin_amdgcn_mfma_f32_16x16x32_bf16(a, b1, acc[1], 0, 0, 0);
            acc[2] = __builtin_amdgcn_mfma_f32_16x16x32_bf16(a, b2, acc[2], 0, 0, 0);
            acc[3] = __builtin_amdgcn_mfma_f32_16x16x32_bf16(a, b3, acc[3], 0, 0, 0);
        }

        if (wv != 0) {
#pragma unroll
            for (int g = 0; g < 4; ++g)
                *(f32x4*)&sm->zp[wv - 1][g][lane][0] = acc[g];
        }
    }
    __syncthreads();   // ALL 16 waves
    if (wv == 0) {
#pragma unroll
        for (int g = 0; g < 4; ++g) {
#pragma unroll
            for (int w = 0; w < 7; ++w)
                acc[g] += *(const f32x4*)&sm->zp[w][g][lane][0];
        }
        const float bI = bih[j]           + bhh[j];
        const float bF = bih[HFS + j]     + bhh[HFS + j];
        const float bG = bih[2 * HFS + j] + bhh[2 * HFS + j];
        const float bO = bih[3 * HFS + j] + bhh[3 * HFS + j];
#pragma unroll
        for (int r = 0; r < 4; ++r) {
            int m   = bgr * 16 + quad * 4 + r;  // C/D row = batch
            int idx = m * HFS + j;
            float iv = sigf(acc[0][r] + bI);
            float fv = sigf(acc[1][r] + bF);
            float gv = tanhf_(acc[2][r] + bG);
            float ov = sigf(acc[3][r] + bO);
            float cn = fv * cst[idx] + iv * gv;
            cst[idx] = cn;
            sm->hT[quad * 4 + r][l16] = ov * tanhf_(cn);
        }
        // transpose & coherent-store packed h (4 bf16 per lane); wave-internal LDS RAW
        float h0 = sm->hT[l16][quad * 4 + 0];
        float h1 = sm->hT[l16][quad * 4 + 1];
        float h2 = sm->hT[l16][quad * 4 + 2];
        float h3 = sm->hT[l16][quad * 4 + 3];
        stu64(hout + (long)(bgr * 16 + l16) * HFS + jsl * 16 + quad * 4,
              packbf4(h0, h1, h2, h3));
    }
}

// ---------------- attention phase (block = (b, sp), all 1024 threads) ----------------
// KVQ: key/val are int8 with per-row scales; else f32 straight from inputs.
template <bool KVQ>
static __device__ __forceinline__ void attn_phase(
    int blk, int tid,
    const void* keyp, const void* valp,
    const float* __restrict__ kscale, const float* __restrict__ vscale,
    const int* __restrict__ Llen,
    const unsigned short* __restrict__ hbv,
    const unsigned short* __restrict__ Wqb, const float* __restrict__ bq,
    float* __restrict__ attM, float* __restrict__ attS, float* __restrict__ attC,
    SmAttn* sm)
{
    const int b     = blk >> 1;
    const int sp    = blk & 1;
    const int L     = Llen[b];
    const int rhalf = (L + 1) >> 1;               // balanced split boundary
    const int rbase = sp * rhalf;
    int nv = L - rbase;
    if (nv > rhalf) nv = rhalf;
    // L >= RAL/2 always (lengths in [512,1024]) so nv >= 1; no early-out needed

    if (tid < 128) {   // coherent-load hb row, 4 bf16 per thread
        unsigned long long q = ldu64(hbv + (long)b * HFS + tid * 4);
        sm->hb_l[tid * 4 + 0] = bflo((unsigned)( q        & 0xffffu));
        sm->hb_l[tid * 4 + 1] = bflo((unsigned)((q >> 16) & 0xffffu));
        sm->hb_l[tid * 4 + 2] = bflo((unsigned)((q >> 32) & 0xffffu));
        sm->hb_l[tid * 4 + 3] = bflo((unsigned)((q >> 48) & 0xffffu));
    }
    __syncthreads();

    // query: 4 threads per output col, 128-wide K chunks (Wq is L2-hot)
    {
        const int c  = tid >> 2;
        const int jj = tid & 3;
        const unsigned short* wr = Wqb + (long)c * HFS + jj * 128;
        const float* xr = &sm->hb_l[jj * 128];
        float qa = 0.0f;
#pragma unroll
        for (int k = 0; k < 128; k += 8) {
            uint4 u = *(const uint4*)(wr + k);
            float4 h0 = *(const float4*)(xr + k);
            float4 h1 = *(const float4*)(xr + k + 4);
            qa += bflo(u.x) * h0.x + bfhi(u.x) * h0.y
                + bflo(u.y) * h0.z + bfhi(u.y) * h0.w
                + bflo(u.z) * h1.x + bfhi(u.z) * h1.y
                + bflo(u.w) * h1.z + bfhi(u.w) * h1.w;
        }
        qa += __shfl_xor(qa, 1);
        qa += __shfl_xor(qa, 2);
        if (jj == 0) sm->q_lds[c] = qa + bq[c];
    }
    __syncthreads();

    // energy: 4 threads per row (64 contiguous channels each), 256 rows per pass
    {
        const int jj   = tid & 3;
        const int rloc = tid >> 2;      // 0..255
        for (int r0 = 0; r0 < nv; r0 += 256) {
            const int r = r0 + rloc;
            float acc = 0.0f;
            if (r < nv) {
                if (KVQ) {
                    const signed char* kp = (const signed char*)keyp
                        + ((long)b * RAL + rbase + r) * CS + jj * 64;
#pragma unroll
                    for (int i = 0; i < 4; ++i) {
                        uint4 u = *(const uint4*)(kp + i * 16);
                        const float* qp = &sm->q_lds[jj * 64 + i * 16];
                        acc += dot4i8(u.x, qp)     + dot4i8(u.y, qp + 4)
                             + dot4i8(u.z, qp + 8) + dot4i8(u.w, qp + 12);
                    }
                } else {
                    const float* kp = (const float*)keyp
                        + ((long)b * RAL + rbase + r) * CS + jj * 64;
#pragma unroll
                    for (int i = 0; i < 16; ++i) {
                        float4 kv = *(const float4*)(kp + i * 4);
                        float4 qa = *(const float4*)&sm->q_lds[jj * 64 + i * 4];
                        acc += kv.x * qa.x + kv.y * qa.y + kv.z * qa.z + kv.w * qa.w;
                    }
                }
            }
            acc += __shfl_xor(acc, 1);
            acc += __shfl_xor(acc, 2);
            if (jj == 0 && r < nv) {
                if (KVQ) acc *= kscale[(long)b * RAL + rbase + r];
                sm->e_lds[r] = acc;
            }
        }
    }
    __syncthreads();

    // local softmax stats (nv <= 512, one row per thread; 16-wave reduce)
    float pm = (tid < nv) ? sm->e_lds[tid] : -1e30f;
#pragma unroll
    for (int s = 32; s > 0; s >>= 1) pm = fmaxf(pm, __shfl_xor(pm, s));
    if ((tid & 63) == 0) sm->red[tid >> 6] = pm;
    __syncthreads();
    float M = sm->red[0];
#pragma unroll
    for (int i = 1; i < 16; ++i) M = fmaxf(M, sm->red[i]);

    float ps = 0.0f;
    if (tid < nv) {
        float v = __expf(sm->e_lds[tid] - M);
        ps = v;   // S accumulates UNSCALED exp
        // fold per-row val scale into the context weight
        sm->e_lds[tid] = KVQ ? v * vscale[(long)b * RAL + rbase + tid] : v;
    }
#pragma unroll
    for (int s = 32; s > 0; s >>= 1) ps += __shfl_xor(ps, s);
    if ((tid & 63) == 0) sm->red[16 + (tid >> 6)] = ps;
    __syncthreads();
    float S = 0.0f;
#pragma unroll
    for (int i = 0; i < 16; ++i) S += sm->red[16 + i];

    if (tid == 0) {
        stu32(attM + b * NSPLIT + sp, fcb(M));
        stu32(attS + b * NSPLIT + sp, fcb(S));
    }

    // partial context (unnormalized): 32 row-groups, lane owns 8 contiguous channels
    {
        const int rg = tid >> 5;         // 0..31
        const int c8 = (tid & 31) * 8;   // 0..248
        float a0=0.f,a1=0.f,a2=0.f,a3=0.f,a4=0.f,a5=0.f,a6=0.f,a7=0.f;
        if (KVQ) {
            const signed char* vb = (const signed char*)valp
                + ((long)b * RAL + rbase) * CS + c8;
            int r = rg;
            for (; r + 224 < nv; r += 256) {          // 8-deep
                uint2 u[8]; float w[8];
#pragma unroll
                for (int k = 0; k < 8; ++k) u[k] = *(const uint2*)(vb + (long)(r + 32 * k) * CS);
#pragma unroll
                for (int k = 0; k < 8; ++k) w[k] = sm->e_lds[r + 32 * k];
#pragma unroll
                for (int k = 0; k < 8; ++k) {
                    a0 += w[k] * i8f(u[k].x);       a1 += w[k] * i8f(u[k].x >> 8);
                    a2 += w[k] * i8f(u[k].x >> 16); a3 += w[k] * i8f(u[k].x >> 24);
                    a4 += w[k] * i8f(u[k].y);       a5 += w[k] * i8f(u[k].y >> 8);
                    a6 += w[k] * i8f(u[k].y >> 16); a7 += w[k] * i8f(u[k].y >> 24);
                }
            }
            for (; r + 96 < nv; r += 128) {           // 4-deep
                uint2 u[4]; float w[4];
#pragma unroll
                for (int k = 0; k < 4; ++k) u[k] = *(const uint2*)(vb + (long)(r + 32 * k) * CS);
#pragma unroll
                for (int k = 0; k < 4; ++k) w[k] = sm->e_lds[r + 32 * k];
#pragma unroll
                for (int k = 0; k < 4; ++k) {
                    a0 += w[k] * i8f(u[k].x);       a1 += w[k] * i8f(u[k].x >> 8);
                    a2 += w[k] * i8f(u[k].x >> 16); a3 += w[k] * i8f(u[k].x >> 24);
                    a4 += w[k] * i8f(u[k].y);       a5 += w[k] * i8f(u[k].y >> 8);
                    a6 += w[k] * i8f(u[k].y >> 16); a7 += w[k] * i8f(u[k].y >> 24);
                }
            }
            for (; r < nv; r += 32) {
                uint2 u = *(const uint2*)(vb + (long)r * CS);
                float w = sm->e_lds[r];
                a0 += w * i8f(u.x);       a1 += w * i8f(u.x >> 8);
                a2 += w * i8f(u.x >> 16); a3 += w * i8f(u.x >> 24);
                a4 += w * i8f(u.y);       a5 += w * i8f(u.y >> 8);
                a6 += w * i8f(u.y >> 16); a7 += w * i8f(u.y >> 24);
            }
        } else {
            const float* vb = (const float*)valp + ((long)b * RAL + rbase) * CS + c8;
            int r = rg;
            for (; r + 96 < nv; r += 128) {
                float4 v0[4], v1[4]; float w[4];
#pragma unroll
                for (int k = 0; k < 4; ++k) {
                    v0[k] = *(const float4*)(vb + (long)(r + 32 * k) * CS);
                    v1[k] = *(const float4*)(vb + (long)(r + 32 * k) * CS + 4);
                }
#pragma unroll
                for (int k = 0; k < 4; ++k) w[k] = sm->e_lds[r + 32 * k];
#pragma unroll
                for (int k = 0; k < 4; ++k) {
                    a0 += w[k] * v0[k].x; a1 += w[k] * v0[k].y;
                    a2 += w[k] * v0[k].z; a3 += w[k] * v0[k].w;
                    a4 += w[k] * v1[k].x; a5 += w[k] * v1[k].y;
                    a6 += w[k] * v1[k].z; a7 += w[k] * v1[k].w;
                }
            }
            for (; r < nv; r += 32) {
                float4 v0 = *(const float4*)(vb + (long)r * CS);
                float4 v1 = *(const float4*)(vb + (long)r * CS + 4);
                float w = sm->e_lds[r];
                a0 += w * v0.x; a1 += w * v0.y; a2 += w * v0.z; a3 += w * v0.w;
                a4 += w * v1.x; a5 += w * v1.y; a6 += w * v1.z; a7 += w * v1.w;
            }
        }
        float4 o0 = {a0, a1, a2, a3};
        float4 o1 = {a4, a5, a6, a7};
        *(float4*)&sm->ctxp[rg][c8]     = o0;
        *(float4*)&sm->ctxp[rg][c8 + 4] = o1;
    }
    __syncthreads();

    if (tid < CS) {
        float cv = 0.0f;
#pragma unroll
        for (int g = 0; g < 32; ++g) cv += sm->ctxp[g][tid];
        stu32(attC + ((long)b * NSPLIT + sp) * CS + tid, fcb(cv));   // unnormalized
    }
}

// ---------------- logits: 512-thread span; block = (16-batch, 1-2 vocab) slice ----------------
static __device__ __forceinline__ void logits_phase(
    int blk, int tid,   // tid in [0,512)
    const unsigned short* __restrict__ hb,
    const float* __restrict__ attM, const float* __restrict__ attS,
    const float* __restrict__ attC,
    const float* __restrict__ Wc, const float* __restrict__ bc,
    float* __restrict__ outp, int tOut)
{
    const int bgr  = blk >> 5;        // 0..7
    const int vsl  = blk & 31;        // 0..31
    const int bloc = tid >> 5;        // 0..15
    const int jj   = tid & 31;        // 0..31
    const int b    = bgr * 16 + bloc;

    float Ms[NSPLIT], Ss[NSPLIT], wgt[NSPLIT];
#pragma unroll
    for (int s = 0; s < NSPLIT; ++s) {
        Ms[s] = bcf(ldu32(attM + b * NSPLIT + s));
        Ss[s] = bcf(ldu32(attS + b * NSPLIT + s));
    }
    float mm = Ms[0];
#pragma unroll
    for (int s = 1; s < NSPLIT; ++s) mm = fmaxf(mm, Ms[s]);
    float den = 0.f;
#pragma unroll
    for (int s = 0; s < NSPLIT; ++s) { wgt[s] = __expf(Ms[s] - mm); den += wgt[s] * Ss[s]; }
    float inv = 1.0f / den;
#pragma unroll
    for (int s = 0; s < NSPLIT; ++s) wgt[s] *= inv;

    float xh[16];
    const unsigned short* hp = hb + (long)b * HFS + jj * 16;
#pragma unroll
    for (int g = 0; g < 4; ++g) {
        unsigned long long q = ldu64(hp + g * 4);
        xh[g * 4 + 0] = bflo((unsigned)( q        & 0xffffu));
        xh[g * 4 + 1] = bflo((unsigned)((q >> 16) & 0xffffu));
        xh[g * 4 + 2] = bflo((unsigned)((q >> 32) & 0xffffu));
        xh[g * 4 + 3] = bflo((unsigned)((q >> 48) & 0xffffu));
    }
    float xc[8];
    const float* cb = attC + (long)b * NSPLIT * CS + jj * 8;
#pragma unroll
    for (int g = 0; g < 4; ++g) {
        float x0 = 0.f, x1 = 0.f;
#pragma unroll
        for (int s = 0; s < NSPLIT; ++s) {
            unsigned long long q = ldu64(cb + (long)s * CS + g * 2);
            x0 += wgt[s] * bcf((unsigned)q);
            x1 += wgt[s] * bcf((unsigned)(q >> 32));
        }
        xc[g * 2]     = x0;
        xc[g * 2 + 1] = x1;
    }

#pragma unroll
    for (int vv = 0; vv < 2; ++vv) {
        int v = vsl + vv * 32;
        if (v >= VOC) break;
        const float* wr = Wc + (long)v * (HFS + CS);
        float part = 0.0f;
#pragma unroll
        for (int g = 0; g < 4; ++g) {
            float4 wv4 = *(const float4*)(wr + jj * 16 + g * 4);
            part += wv4.x * xh[g * 4 + 0] + wv4.y * xh[g * 4 + 1]
                  + wv4.z * xh[g * 4 + 2] + wv4.w * xh[g * 4 + 3];
        }
#pragma unroll
        for (int g = 0; g < 2; ++g) {
            float4 wv4 = *(const float4*)(wr + HFS + jj * 8 + g * 4);
            part += wv4.x * xc[g * 4 + 0] + wv4.y * xc[g * 4 + 1]
                  + wv4.z * xc[g * 4 + 2] + wv4.w * xc[g * 4 + 3];
        }
        part += __shfl_xor(part, 1);
        part += __shfl_xor(part, 2);
        part += __shfl_xor(part, 4);
        part += __shfl_xor(part, 8);
        part += __shfl_xor(part, 16);
        if (jj == 0)
            outp[((long)b * LAL + tOut) * VOC + v] = part + bc[v];
    }
}

// ---------------- fused kernel: 256 blocks x 1024 threads, 3 barriers/step ----------------
template <bool KVQ>
__global__ __launch_bounds__(1024, 4) void fused_kernel(PParams P)
{
    __shared__ __align__(16) unsigned char smraw[SMSZ];
    SmLstm* smL = (SmLstm*)smraw;
    SmAttn* smA = (SmAttn*)smraw;

    const int blk = blockIdx.x;
    const int tid = threadIdx.x;
    const int wv  = tid >> 6;
    int round = 0;

    for (int t = 0; t < LAL; ++t) {
        const unsigned short* haIn  = P.ha   + (t & 1) * (BS * HFS);
        unsigned short*       haOut = P.ha   + ((t + 1) & 1) * (BS * HFS);
        const unsigned short* hbIn  = P.hbuf + (t & 1) * (BS * HFS);
        unsigned short*       hbOut = P.hbuf + ((t + 1) & 1) * (BS * HFS);

        // phase 1: LSTM A (waves 0-7)
        lstm_phase<true>(blk, tid, nullptr, P.attM, P.attS, P.attC,
                         P.embb, P.y, t, haIn,
                         P.WihA, P.WhhA, P.bihA, P.bhhA, P.ca, haOut, smL);
        gbar(P.grp, P.root, blk, round++);

        // phase 2: LSTM B (waves 0-7) CONCURRENT with logits(t-1) (waves 8-15)
        if (wv >= 8 && t > 0)
            logits_phase(blk, tid - 512, hbIn, P.attM, P.attS, P.attC,
                         P.Wc, P.bc, P.outp, t - 1);
        lstm_phase<false>(blk, tid, haOut, nullptr, nullptr, nullptr,
                          nullptr, nullptr, t, hbIn,
                          P.WihB, P.WhhB, P.bihB, P.bhhB, P.cbuf, hbOut, smL);
        gbar(P.grp, P.root, blk, round++);

        // phase 3: attention partials (all 16 waves; in-block q)
        attn_phase<KVQ>(blk, tid, P.keyp, P.valp, P.kscale, P.vscale, P.Llen,
                        hbOut, P.Wqb, P.bq, P.attM, P.attS, P.attC, smA);
        gbar(P.grp, P.root, blk, round++);
    }
    // final logits (t = LAL-1); hb(LAL-1) lives in hbuf[LAL & 1] == hbuf[0]
    if (tid < 512)
        logits_phase(blk, tid, P.hbuf + (LAL & 1) * (BS * HFS),
                     P.attM, P.attS, P.attC, P.Wc, P.bc, P.outp, LAL - 1);
}

// ---------------- host ----------------
extern "C" void kernel_launch(void* const* d_in, const int* in_sizes, int n_in,
                              void* d_out, int out_size, void* d_ws, size_t ws_size,
                              hipStream_t stream)
{
    (void)in_sizes; (void)n_in; (void)out_size;
    const float* keyf  = (const float*)d_in[0];
    const float* valf  = (const float*)d_in[1];
    const float* mask  = (const float*)d_in[2];
    const float* embf  = (const float*)d_in[3];
    const float* WihAf = (const float*)d_in[4];
    const float* WhhAf = (const float*)d_in[5];
    const float* bihA  = (const float*)d_in[6];
    const float* bhhA  = (const float*)d_in[7];
    const float* WihBf = (const float*)d_in[8];
    const float* WhhBf = (const float*)d_in[9];
    const float* bihB  = (const float*)d_in[10];
    const float* bhhB  = (const float*)d_in[11];
    const float* Wqf   = (const float*)d_in[12];
    const float* bq    = (const float*)d_in[13];
    const float* Wc    = (const float*)d_in[14];
    const float* bc    = (const float*)d_in[15];
    const int*   y     = (const int*)d_in[16];
    float* outp = (float*)d_out;

    size_t off = 0;
    auto take = [&](size_t bytes) -> void* {
        void* p = (char*)d_ws + off;
        off += (bytes + 255) & ~(size_t)255;
        return p;
    };

    // ---- zero-initialized state block (memset every launch; includes barrier counters) ----
    unsigned short* ha    = (unsigned short*)take((size_t)2 * BS * HFS * 2); // double-buffered
    unsigned short* hbuf  = (unsigned short*)take((size_t)2 * BS * HFS * 2); // double-buffered
    float*          ca    = (float*)take((size_t)BS * HFS * 4);
    float*          cbuf  = (float*)take((size_t)BS * HFS * 4);
    float*          attM  = (float*)take((size_t)BS * NSPLIT * 4);
    float*          attS  = (float*)take((size_t)BS * NSPLIT * 4);
    float*          attC  = (float*)take((size_t)BS * NSPLIT * CS * 4);
    unsigned*       grp   = (unsigned*)take((size_t)16 * 32 * 4);   // padded group counters
    unsigned*       root  = (unsigned*)take((size_t)32 * 4);
    size_t stateBytes = off;

    int*            Llen  = (int*)take((size_t)BS * 4);
    unsigned short* embb  = (unsigned short*)take((size_t)VOC * EMB * 2);
    unsigned short* WihAb = (unsigned short*)take((size_t)4 * HFS * HFS * 2);
    unsigned short* WhhAb = (unsigned short*)take((size_t)4 * HFS * HFS * 2);
    unsigned short* WihBb = (unsigned short*)take((size_t)4 * HFS * HFS * 2);
    unsigned short* WhhBb = (unsigned short*)take((size_t)4 * HFS * HFS * 2);
    unsigned short* Wqb   = (unsigned short*)take((size_t)CS * HFS * 2);

    // --- int8 KV + per-row scales (f32 fallback if ws too small) ---
    const size_t q8Bytes = (size_t)BS * RAL * CS;        // 33.5 MB each
    const size_t scBytes = (size_t)BS * RAL * 4;         // 512 KB each
    signed char* key8 = nullptr;
    signed char* val8 = nullptr;
    float* kscale = nullptr;
    float* vscale = nullptr;
    bool kvq = false;
    if (off + 2 * (q8Bytes + 256) + 2 * (scBytes + 256) <= ws_size) {
        key8   = (signed char*)take(q8Bytes);
        val8   = (signed char*)take(q8Bytes);
        kscale = (float*)take(scBytes);
        vscale = (float*)take(scBytes);
        kvq = true;
    }

    hipMemsetAsync(d_ws, 0, stateBytes, stream);
    len_kernel<<<dim3(BS), dim3(256), 0, stream>>>(mask, Llen, attS);

    auto cvt = [&](const float* src, unsigned short* dst, long n) {
        int n4 = (int)(n / 4);
        int blocks = (n4 + 255) / 256;
        if (blocks > 8192) blocks = 8192;
        cvt4_kernel<<<dim3(blocks), dim3(256), 0, stream>>>((const float4*)src, (ushort4*)dst, n4);
    };
    cvt(embf,  embb,  (long)VOC * EMB);
    cvt(WihAf, WihAb, (long)4 * HFS * HFS);
    cvt(WhhAf, WhhAb, (long)4 * HFS * HFS);
    cvt(WihBf, WihBb, (long)4 * HFS * HFS);
    cvt(WhhBf, WhhBb, (long)4 * HFS * HFS);
    cvt(Wqf,   Wqb,   (long)CS * HFS);
    if (kvq) {
        const int nrows = BS * RAL;
        quant8_kernel<<<dim3(nrows / 4), dim3(256), 0, stream>>>(keyf, key8, kscale, nrows);
        quant8_kernel<<<dim3(nrows / 4), dim3(256), 0, stream>>>(valf, val8, vscale, nrows);
    }

    PParams prm;
    prm.keyp = kvq ? (const void*)key8 : (const void*)keyf;
    prm.valp = kvq ? (const void*)val8 : (const void*)valf;
    prm.kscale = kscale; prm.vscale = vscale;
    prm.Llen = Llen; prm.y = y;
    prm.embb = embb;
    prm.WihA = WihAb; prm.WhhA = WhhAb; prm.bihA = bihA; prm.bhhA = bhhA;
    prm.WihB = WihBb; prm.WhhB = WhhBb; prm.bihB = bihB; prm.bhhB = bhhB;
    prm.Wqb = Wqb; prm.bq = bq; prm.Wc = Wc; prm.bc = bc;
    prm.ha = ha; prm.hbuf = hbuf; prm.ca = ca; prm.cbuf = cbuf;
    prm.attM = attM; prm.attS = attS; prm.attC = attC;
    prm.grp = grp; prm.root = root;
    prm.outp = outp;

    void* kargs[] = { &prm };
    if (kvq)
        hipLaunchCooperativeKernel(reinterpret_cast<void*>(&fused_kernel<true>),
                                   dim3(NBLK), dim3(1024), kargs, 0, stream);
    else
        hipLaunchCooperativeKernel(reinterpret_cast<void*>(&fused_kernel<false>),
                                   dim3(NBLK), dim3(1024), kargs, 0, stream);
}